// Round 3
// baseline (110.475 us; speedup 1.0000x reference)
//
#include <hip/hip_runtime.h>
#include <hip/hip_bf16.h>
#include <hip/hip_fp8.h>
#include <math.h>

#define BROWS 4096
#define DIM   512
#define YEMB_B 2097152   // 4096*512 bytes, offset of emb rows in Yq (fp8)
#define TSTRIDE 191      // tile stride (tiles are 192 wide, overlap by 1)
#define NT 22            // tiles per dim; triangle tiles = 22*23/2 = 253

typedef float f32x4 __attribute__((ext_vector_type(4)));

// ---------------------------------------------------------------------------
// prep4: wave-per-row, no barriers. 8192 rows (low then emb), 4 rows/block.
// L2-normalize -> fp8 e4m3 row in Yq; s=sum(y^2), r=sum(y) from f32 y.
// (verified R12-R18: absmax 0.0)
// ---------------------------------------------------------------------------
__global__ __launch_bounds__(256) void prep4_kernel(
    const float* __restrict__ low, const float* __restrict__ emb,
    unsigned char* __restrict__ Yq,
    float* __restrict__ s_l, float* __restrict__ r_l,
    float* __restrict__ s_e, float* __restrict__ r_e,
    float* __restrict__ out) {
  const int tid = threadIdx.x;
  const int lane = tid & 63, wid = tid >> 6;
  const int rid = blockIdx.x * 4 + wid;          // 0..8191
  if (blockIdx.x == 0 && tid == 0) out[0] = 0.f;

  const bool is_low = (rid < BROWS);
  const int row = is_low ? rid : rid - BROWS;
  const float* x = (is_low ? low : emb) + (size_t)row * DIM;

  const float4 v0 = ((const float4*)x)[lane * 2];
  const float4 v1 = ((const float4*)x)[lane * 2 + 1];

  float ss = v0.x * v0.x + v0.y * v0.y + v0.z * v0.z + v0.w * v0.w +
             v1.x * v1.x + v1.y * v1.y + v1.z * v1.z + v1.w * v1.w;
#pragma unroll
  for (int o = 1; o < 64; o <<= 1) ss += __shfl_xor(ss, o, 64);
  const float inv = 1.0f / fmaxf(sqrtf(ss), 1e-12f);

  float y[8] = {v0.x * inv, v0.y * inv, v0.z * inv, v0.w * inv,
                v1.x * inv, v1.y * inv, v1.z * inv, v1.w * inv};

  union { unsigned char b[8]; unsigned long long u; } pk;
  float sv = 0.f, rv = 0.f;
#pragma unroll
  for (int i = 0; i < 8; ++i) {
    pk.b[i] = __hip_fp8_e4m3(y[i]).__x;   // OCP e4m3fn, HW RNE
    sv += y[i] * y[i];
    rv += y[i];
  }
  ((unsigned long long*)(Yq + (size_t)rid * 512))[lane] = pk.u;

#pragma unroll
  for (int o = 1; o < 64; o <<= 1) {
    sv += __shfl_xor(sv, o, 64);
    rv += __shfl_xor(rv, o, 64);
  }
  if (lane == 0) {
    (is_low ? s_l : s_e)[row] = sv;
    (is_low ? r_l : r_e)[row] = rv;
  }
}

// ---------------------------------------------------------------------------
// R19 (resubmit R20: round 2's bench never acquired a GPU).
// Occupancy redesign. Each 192x192 tile -> TWO independent col-half
// blocks (192 rows x 96 cols), 256 thr = 4 waves of the verified 48x96
// wave tile (wr = wid). 506 blocks, LDS ~80.1 KB -> 2 blocks/CU: two
// barrier-independent blocks per CU fill each other's stall phases
// (R18 post-mortem: 1 block/CU lockstep left MfmaUtil at 15.5%).
// Left half (coff=0) computes one extra B-frag column v=6 (cols 96..111)
// so the pass-1 col-95/96 pair handoff is in-wave (hand_d deleted);
// right half's last col (tile col 191) is filtered, needs no handoff.
// K-loop: BK=64, 8 rounds, double-buffered 2x38,912 B, counted vmcnt.
// Staging slot map per buffer: 304 row-pairs (A_low 96, A_emb 96,
// B_low 56, B_emb 56) x 8 chunks of 16 B; slot chunk cc&3 holds global
// chunk (cc&3)^(rp_local&3); cc>>2 = row parity. Frag reads are typed
// __shared__ long indexing -> guaranteed ds_read_b64.
// MFMA: f32_16x16x32_fp8_fp8; C/D: col=lane&15, row=(lane>>4)*4+reg.
// ---------------------------------------------------------------------------
__global__ __launch_bounds__(256, 2) void fused_sym_kernel(
    const unsigned char* __restrict__ Yq,
    const float* __restrict__ s_l, const float* __restrict__ r_l,
    const float* __restrict__ s_e, const float* __restrict__ r_e,
    float* __restrict__ out) {
  __shared__ __align__(16) long lds_l[9728];   // 2 x 38,912 B staging
  __shared__ float hand_t[3][96][2];   // dl/de at row 48*wr for wr-1, 96 cols
  __shared__ float sred[4];

  // decode: blockIdx = 2*tri + half
  const int tri = blockIdx.x >> 1;
  const int half = blockIdx.x & 1;
  int rem = tri, br = 0;
  while (rem >= NT - br) { rem -= NT - br; ++br; }
  const int bc = br + rem;
  const bool diag = (br == bc);
  const bool hasv6 = (half == 0);

  const int tid = threadIdx.x;
  const int lane = tid & 63;
  const int wid = tid >> 6;          // 0..3
  const int wr = wid;                // rows 48*wr..48*wr+47
  const int quad = lane >> 4, cpos = lane & 15;
  const int r0 = br * TSTRIDE;
  const int cB = bc * TSTRIDE + half * 96;   // block's first global col
  const int tcbase = half * 96;              // block's first tile-local col

  // ---- staging global offsets: 2432 slots of 16B/round, 10 per thread
  // (threads >=128 do 9) ----
  int goff[10];
#pragma unroll
  for (int s = 0; s < 10; ++s) {
    const int c = tid + 256 * s;        // 0..2559 (>=2432 unused)
    const int rp = c >> 3, cc = c & 7;
    int seg, rpl;
    if (rp < 96)       { seg = 0; rpl = rp;       }
    else if (rp < 192) { seg = 1; rpl = rp - 96;  }
    else if (rp < 248) { seg = 2; rpl = rp - 192; }
    else               { seg = 3; rpl = rp - 248; }
    const int rloc = 2 * rpl + (cc >> 2);
    const int gch = (cc & 3) ^ (rpl & 3);
    int base;
    if (seg == 0)      base = min(r0 + rloc, BROWS - 1) * 512;
    else if (seg == 1) base = YEMB_B + min(r0 + rloc, BROWS - 1) * 512;
    else if (seg == 2) base = min(cB + rloc, BROWS - 1) * 512;
    else               base = YEMB_B + min(cB + rloc, BROWS - 1) * 512;
    goff[s] = base + (gch << 4);
  }

  auto STAGE = [&](int t, int b) {
    const int k0 = t * 64;
#pragma unroll
    for (int s = 0; s < 10; ++s) {
      if (s < 9 || tid < 128)
        __builtin_amdgcn_global_load_lds(
            (const __attribute__((address_space(1))) void*)(Yq + goff[s] + k0),
            (__attribute__((address_space(3))) void*)(
                ((char*)lds_l) + b * 38912 + (tid + 256 * s) * 16),
            16, 0, 0);
    }
  };

  // ---- frag addressing (bytes -> long indices) ----
  // seg bases: A_low 0, A_emb 12288, B_low 24576, B_emb 31744 (no diag
  // redirect: B always staged). row-pair stride 128 B, 16 rows = 1024 B.
  const int RaH = (48 * wr + cpos) >> 1;
  const int s3a = RaH & 3;
  const int aoff = RaH * 128 + (cpos & 1) * 64 + (quad & 1) * 8;
  const int s3b = (cpos >> 1) & 3;
  const int boff = (cpos >> 1) * 128 + (cpos & 1) * 64 + (quad & 1) * 8;
  const int iaL = aoff >> 3;
  const int iaE = (12288 + aoff) >> 3;
  const int ibL = (24576 + boff) >> 3;
  const int ibE = (31744 + boff) >> 3;

  f32x4 accl[3][7], acce[3][7];
#pragma unroll
  for (int u = 0; u < 3; ++u)
#pragma unroll
    for (int v = 0; v < 7; ++v) {
      accl[u][v] = (f32x4)(0.f);
      acce[u][v] = (f32x4)(0.f);
    }

  STAGE(0, 0);   // prologue prefetch

  for (int t = 0; t < 8; ++t) {
    if (t < 7) STAGE(t + 1, (t + 1) & 1);
    // counted wait: round-t loads are the oldest (10 for waves 0-1, 9 for
    // waves 2-3); keep round t+1's in flight.
    if (t == 7)      asm volatile("s_waitcnt vmcnt(0)" ::: "memory");
    else if (wid < 2) asm volatile("s_waitcnt vmcnt(10)" ::: "memory");
    else             asm volatile("s_waitcnt vmcnt(9)" ::: "memory");
    __builtin_amdgcn_s_barrier();
    __builtin_amdgcn_sched_barrier(0);

    const int bo = (t & 1) * 4864;   // buffer offset in longs
#pragma unroll
    for (int kk = 0; kk < 2; ++kk) {
      const int q = 2 * kk + (quad >> 1);          // 16B chunk 0..3
      const int qa2 = ((q ^ s3a) << 1);            // chunk offset in longs
      const int qb2 = ((q ^ s3b) << 1);
      {  // low matrix
        long a[3], b[7];
#pragma unroll
        for (int u = 0; u < 3; ++u) a[u] = lds_l[bo + iaL + qa2 + u * 128];
#pragma unroll
        for (int v = 0; v < 6; ++v) b[v] = lds_l[bo + ibL + qb2 + v * 128];
        if (hasv6) b[6] = lds_l[bo + ibL + qb2 + 768];
        __builtin_amdgcn_s_setprio(1);
#pragma unroll
        for (int u = 0; u < 3; ++u)
#pragma unroll
          for (int v = 0; v < 6; ++v)
            accl[u][v] = __builtin_amdgcn_mfma_f32_16x16x32_fp8_fp8(
                a[u], b[v], accl[u][v], 0, 0, 0);
        if (hasv6) {
#pragma unroll
          for (int u = 0; u < 3; ++u)
            accl[u][6] = __builtin_amdgcn_mfma_f32_16x16x32_fp8_fp8(
                a[u], b[6], accl[u][6], 0, 0, 0);
        }
        __builtin_amdgcn_s_setprio(0);
      }
      {  // emb matrix
        long a[3], b[7];
#pragma unroll
        for (int u = 0; u < 3; ++u) a[u] = lds_l[bo + iaE + qa2 + u * 128];
#pragma unroll
        for (int v = 0; v < 6; ++v) b[v] = lds_l[bo + ibE + qb2 + v * 128];
        if (hasv6) b[6] = lds_l[bo + ibE + qb2 + 768];
        __builtin_amdgcn_s_setprio(1);
#pragma unroll
        for (int u = 0; u < 3; ++u)
#pragma unroll
          for (int v = 0; v < 6; ++v)
            acce[u][v] = __builtin_amdgcn_mfma_f32_16x16x32_fp8_fp8(
                a[u], b[v], acce[u][v], 0, 0, 0);
        if (hasv6) {
#pragma unroll
          for (int u = 0; u < 3; ++u)
            acce[u][6] = __builtin_amdgcn_mfma_f32_16x16x32_fp8_fp8(
                a[u], b[6], acce[u][6], 0, 0, 0);
        }
        __builtin_amdgcn_s_setprio(0);
      }
    }
    __builtin_amdgcn_sched_barrier(0);
    __builtin_amdgcn_s_barrier();
    __builtin_amdgcn_sched_barrier(0);
  }

  // ---- transform both accs -> distances in place (v=6 incl.; right-half
  // v=6 values are garbage-but-finite and always filtered) ----
  const float epst = (float)DIM * 1e-6f * 1e-6f;
#pragma unroll
  for (int v = 0; v < 7; ++v) {
    const int j = min(cB + 16 * v + cpos, BROWS - 1);
    const float sjl = s_l[j], rjl = r_l[j];
    const float sje = s_e[j], rje = r_e[j];
#pragma unroll
    for (int u = 0; u < 3; ++u)
#pragma unroll
      for (int r = 0; r < 4; ++r) {
        const int i = min(r0 + 48 * wr + 16 * u + 4 * quad + r, BROWS - 1);
        const float sql = s_l[i] + sjl - 2.f * accl[u][v][r] +
                          2e-6f * (r_l[i] - rjl) + epst;
        accl[u][v][r] = sqrtf(fmaxf(sql, 0.f));
        const float sqe = s_e[i] + sje - 2.f * acce[u][v][r] +
                          2e-6f * (r_e[i] - rje) + epst;
        acce[u][v][r] = sqrtf(fmaxf(sqe, 0.f));
      }
  }
  // now: dl in accl, de in acce

  // ---- publish cross-wave boundary rows (row 48*wr -> wr-1) ----
  if (quad == 0 && wr >= 1) {
#pragma unroll
    for (int v = 0; v < 6; ++v) {
      hand_t[wr - 1][16 * v + cpos][0] = accl[0][v][0];
      hand_t[wr - 1][16 * v + cpos][1] = acce[0][v][0];
    }
  }
  __syncthreads();

  float sum = 0.f;

  // ---- pass 1: direct terms (i in rows, pair cols j,j+1) ----
  const int srcin = (lane & 48) | ((cpos + 1) & 15);
#pragma unroll
  for (int u = 0; u < 3; ++u)
#pragma unroll
    for (int r = 0; r < 4; ++r) {
      const int trow = 48 * wr + 16 * u + 4 * quad + r;
      const int i = r0 + trow;
      const bool rowok = (trow <= TSTRIDE - 1) && (i <= BROWS - 2);
#pragma unroll
      for (int v = 0; v < 6; ++v) {
        const float dl1 = accl[u][v][r], de1 = acce[u][v][r];
        float dl2 = __shfl(dl1, srcin, 64);
        float de2 = __shfl(de1, srcin, 64);
        const float dlb = __shfl(accl[u][v + 1][r], lane & 48, 64);
        const float deb = __shfl(acce[u][v + 1][r], lane & 48, 64);
        if (cpos == 15) { dl2 = dlb; de2 = deb; }
        const int tc = tcbase + 16 * v + cpos;   // tile-local col
        const int j = cB + 16 * v + cpos;
        if (rowok && tc <= TSTRIDE - 1 && j <= BROWS - 3) {
          const float aa = dl1 - dl2, bb = de1 - de2;
          const float coeff = (float)((aa > 0.f) - (aa < 0.f)) -
                              (float)((bb > 0.f) - (bb < 0.f));
          sum += coeff * (de2 - de1);
        }
      }
    }

  // ---- pass 2: transposed terms (i in cols, pair rows j,j+1), off-diag only ----
  if (!diag) {
#pragma unroll
    for (int u = 0; u < 3; ++u)
#pragma unroll
      for (int v = 0; v < 6; ++v) {
        const int tc = tcbase + 16 * v + cpos;
        const int ii = cB + 16 * v + cpos;
        const bool colok = (tc <= TSTRIDE - 1) && (ii <= BROWS - 2);
#pragma unroll
        for (int r = 0; r < 4; ++r) {
          const int trow = 48 * wr + 16 * u + 4 * quad + r;
          const int jj = r0 + trow;
          float dl2, de2;
          if (r < 3) {
            dl2 = accl[u][v][r + 1];
            de2 = acce[u][v][r + 1];
          } else {
            const float dlq = __shfl(accl[u][v][0], (lane + 16) & 63, 64);
            const float deq = __shfl(acce[u][v][0], (lane + 16) & 63, 64);
            const int un = (u < 2) ? u + 1 : u;
            const float dlu = __shfl(accl[un][v][0], cpos, 64);
            const float deu = __shfl(acce[un][v][0], cpos, 64);
            if (quad < 3)    { dl2 = dlq; de2 = deq; }
            else if (u < 2)  { dl2 = dlu; de2 = deu; }
            else             { dl2 = hand_t[wr][16 * v + cpos][0];  // wr==3 filtered
                               de2 = hand_t[wr][16 * v + cpos][1]; }
          }
          if (colok && trow <= TSTRIDE - 1 && jj <= BROWS - 3) {
            const float dl1 = accl[u][v][r], de1 = acce[u][v][r];
            const float aa = dl1 - dl2, bb = de1 - de2;
            const float coeff = (float)((aa > 0.f) - (aa < 0.f)) -
                                (float)((bb > 0.f) - (bb < 0.f));
            sum += coeff * (de2 - de1);
          }
        }
      }
  }

  // ---- reduce + atomic ----
#pragma unroll
  for (int o = 32; o; o >>= 1) sum += __shfl_down(sum, o, 64);
  if (lane == 0) sred[wid] = sum;
  __syncthreads();
  if (tid == 0) {
    const float scale = 1.0f / ((float)(BROWS - 1) * (float)(BROWS - 2));
    float t = 0.f;
#pragma unroll
    for (int w = 0; w < 4; ++w) t += sred[w];
    atomicAdd(out, t * scale);
  }
}

// ===========================================================================
extern "C" void kernel_launch(void* const* d_in, const int* in_sizes, int n_in,
                              void* d_out, int out_size, void* d_ws,
                              size_t ws_size, hipStream_t stream) {
  const float* low = (const float*)d_in[0];
  const float* emb = (const float*)d_in[1];
  float* out = (float*)d_out;

  // ws: Yq (2*4096*512 fp8 = 4 MB) then s_l, r_l, s_e, r_e (4096 f32 each)
  unsigned char* Yq = (unsigned char*)d_ws;
  float* s_l = (float*)(Yq + 2 * (size_t)BROWS * DIM);
  float* r_l = s_l + BROWS;
  float* s_e = r_l + BROWS;
  float* r_e = s_e + BROWS;

  prep4_kernel<<<2 * BROWS / 4, 256, 0, stream>>>(low, emb, Yq, s_l, r_l, s_e, r_e, out);
  fused_sym_kernel<<<NT * (NT + 1), 256, 0, stream>>>(Yq, s_l, r_l, s_e, r_e, out);
}